// Round 11
// baseline (441.091 us; speedup 1.0000x reference)
//
#include <hip/hip_runtime.h>
#include <hip/hip_bf16.h>
#include <cmath>

typedef __attribute__((ext_vector_type(8))) short short8;
typedef __attribute__((ext_vector_type(4))) float f32x4;

#define MFMA16(a, b, c) __builtin_amdgcn_mfma_f32_16x16x32_bf16((a), (b), (c), 0, 0, 0)

static constexpr int BB = 16, NN = 2048, DD = 256, HH = 256;

__device__ inline unsigned short f2bf(float f) {
    union { float f; unsigned int u; } v; v.f = f;
    unsigned int r = v.u + 0x7fffu + ((v.u >> 16) & 1u);
    return (unsigned short)(r >> 16);
}
__device__ inline float bf2f(unsigned short u) {
    union { unsigned int u; float f; } v; v.u = ((unsigned int)u) << 16;
    return v.f;
}
__device__ inline float gelu_exact(float x) {
    return 0.5f * x * (1.0f + erff(x * 0.7071067811865475f));
}
__device__ inline void gload_lds16(const void* g, void* l) {
    __builtin_amdgcn_global_load_lds(
        (const __attribute__((address_space(1))) unsigned int*)g,
        (__attribute__((address_space(3))) unsigned int*)l, 16, 0, 0);
}
__device__ inline void fence_mem() { asm volatile("" ::: "memory"); }

// ---- tiled weight transpose: fp32 [256][N] -> bf16 [N][256], coalesced ----
__global__ __launch_bounds__(256) void transposeT_k(const float* __restrict__ W1b,
                                                    const float* __restrict__ Wqkv,
                                                    const float* __restrict__ W2a,
                                                    unsigned short* __restrict__ W1bT,
                                                    unsigned short* __restrict__ WqkvT,
                                                    unsigned short* __restrict__ W2aT) {
    __shared__ float tl[64][65];
    int bid = blockIdx.x;  // 80 blocks: 16 W1b, 48 Wqkv, 16 W2a
    const float* src;
    unsigned short* dst;
    int N, tn, tk;
    if (bid < 16) {
        src = W1b; dst = W1bT; N = 256; tn = bid & 3; tk = bid >> 2;
    } else if (bid < 64) {
        int t2 = bid - 16;
        src = Wqkv; dst = WqkvT; N = 768; tn = t2 % 12; tk = t2 / 12;
    } else {
        int t2 = bid - 64;
        src = W2a; dst = W2aT; N = 256; tn = t2 & 3; tk = t2 >> 2;
    }
    int n0 = tn * 64, k0 = tk * 64;
    int t = threadIdx.x;
#pragma unroll
    for (int j = 0; j < 4; j++) {
        int row = (t >> 4) * 4 + j;
        f32x4 v = *(const f32x4*)(src + (size_t)(k0 + row) * N + n0 + (t & 15) * 4);
#pragma unroll
        for (int e = 0; e < 4; e++) tl[row][(t & 15) * 4 + e] = v[e];
    }
    __syncthreads();
    int n = t >> 2, cb = (t & 3) * 16;
    short8 a, b;
#pragma unroll
    for (int e = 0; e < 8; e++) {
        a[e] = (short)f2bf(tl[cb + e][n]);
        b[e] = (short)f2bf(tl[cb + 8 + e][n]);
    }
    *(short8*)(dst + (size_t)(n0 + n) * 256 + k0 + cb) = a;
    *(short8*)(dst + (size_t)(n0 + n) * 256 + k0 + cb + 8) = b;
}

// ---- fused FFN1 + qkv, 8 waves: (qsub = w>>1, nhalf = w&1), acc[8] ----
__global__ __launch_bounds__(512) void ffn_qkv_k(const float* __restrict__ x,
                                                 const float* __restrict__ grd,
                                                 const float* __restrict__ W1a,
                                                 const float* __restrict__ b1a,
                                                 const unsigned short* __restrict__ W1bT,
                                                 const float* __restrict__ b1b,
                                                 const unsigned short* __restrict__ WqkvT,
                                                 unsigned short* __restrict__ qo,
                                                 unsigned short* __restrict__ ko,
                                                 unsigned short* __restrict__ vo) {
    __shared__ unsigned short h_lds[4][16 * 256];  // per qsub, written by both nhalves
    const int w = threadIdx.x >> 6, lane = threadIdx.x & 63;
    const int c = lane & 15, g = lane >> 4;
    const int qsub = w >> 1, nh = w & 1;
    const int rb = blockIdx.x * 64 + qsub * 16;
    const int bb = (blockIdx.x * 64) >> 11;
    const int rowinb = (rb & (NN - 1)) + c;

    // t A-fragments (full K, per-lane; redundant across nhalf pair — cheap)
    const int p = rb + c;
    const float xv = x[p];
    const float gv = grd[p & (NN - 1)];
    short8 tf[8];
#pragma unroll
    for (int kc = 0; kc < 8; kc++) {
        int j0 = kc * 32 + g * 8;
#pragma unroll
        for (int e = 0; e < 8; e += 4) {
            f32x4 wa = *(const f32x4*)(W1a + j0 + e);
            f32x4 wb = *(const f32x4*)(W1a + 256 + j0 + e);
            f32x4 ba = *(const f32x4*)(b1a + j0 + e);
#pragma unroll
            for (int q = 0; q < 4; q++) {
                float v = xv * wa[q] + gv * wb[q] + ba[q];
                tf[kc][e + q] = (short)f2bf(gelu_exact(v));
            }
        }
    }

    // h = t @ W1b + b1b  (own col-half)
    f32x4 acc[8];
#pragma unroll
    for (int n = 0; n < 8; n++) acc[n] = (f32x4){0.f, 0.f, 0.f, 0.f};
#pragma unroll
    for (int kc = 0; kc < 8; kc++) {
        short8 a = tf[kc];
#pragma unroll
        for (int n = 0; n < 8; n++) {
            short8 bfr = *(const short8*)(W1bT + (size_t)(nh * 128 + n * 16 + c) * 256 + kc * 32 + g * 8);
            acc[n] = MFMA16(a, bfr, acc[n]);
        }
    }
    unsigned short* hl = &h_lds[qsub][0];
#pragma unroll
    for (int n = 0; n < 8; n++) {
        int col = nh * 128 + n * 16 + c;
        float bv = b1b[col];
#pragma unroll
        for (int r = 0; r < 4; r++) {
            int row = g * 4 + r;
            hl[row * 256 + (col ^ ((row & 7) << 3))] = f2bf(acc[n][r] + bv);
        }
    }
    __syncthreads();
    short8 hf[8];
#pragma unroll
    for (int kc = 0; kc < 8; kc++) {
        hf[kc] = *(const short8*)(hl + c * 256 + ((kc * 32 + g * 8) ^ ((c & 7) << 3)));
    }

    // q (scaled 1/16), own col-half
#pragma unroll
    for (int n = 0; n < 8; n++) acc[n] = (f32x4){0.f, 0.f, 0.f, 0.f};
#pragma unroll
    for (int kc = 0; kc < 8; kc++) {
        short8 a = hf[kc];
#pragma unroll
        for (int n = 0; n < 8; n++) {
            short8 bfr = *(const short8*)(WqkvT + (size_t)(nh * 128 + n * 16 + c) * 256 + kc * 32 + g * 8);
            acc[n] = MFMA16(a, bfr, acc[n]);
        }
    }
#pragma unroll
    for (int n = 0; n < 8; n++)
#pragma unroll
        for (int r = 0; r < 4; r++)
            qo[(size_t)(rb + g * 4 + r) * 256 + nh * 128 + n * 16 + c] = f2bf(acc[n][r] * 0.0625f);

    // k
#pragma unroll
    for (int n = 0; n < 8; n++) acc[n] = (f32x4){0.f, 0.f, 0.f, 0.f};
#pragma unroll
    for (int kc = 0; kc < 8; kc++) {
        short8 a = hf[kc];
#pragma unroll
        for (int n = 0; n < 8; n++) {
            short8 bfr = *(const short8*)(WqkvT + (size_t)(256 + nh * 128 + n * 16 + c) * 256 + kc * 32 + g * 8);
            acc[n] = MFMA16(a, bfr, acc[n]);
        }
    }
#pragma unroll
    for (int n = 0; n < 8; n++)
#pragma unroll
        for (int r = 0; r < 4; r++)
            ko[(size_t)(rb + g * 4 + r) * 256 + nh * 128 + n * 16 + c] = f2bf(acc[n][r]);

    // v (swapped operands -> v^T), own d-half
#pragma unroll
    for (int m = 0; m < 8; m++) acc[m] = (f32x4){0.f, 0.f, 0.f, 0.f};
#pragma unroll
    for (int kc = 0; kc < 8; kc++) {
        short8 b = hf[kc];
#pragma unroll
        for (int m = 0; m < 8; m++) {
            short8 afr = *(const short8*)(WqkvT + (size_t)(512 + nh * 128 + m * 16 + c) * 256 + kc * 32 + g * 8);
            acc[m] = MFMA16(afr, b, acc[m]);
        }
    }
#pragma unroll
    for (int m = 0; m < 8; m++) {
#pragma unroll
        for (int r = 0; r < 4; r++) {
            int dcol = nh * 128 + m * 16 + g * 4 + r;
            vo[((size_t)(bb * 256 + dcol)) * NN + rowinb] = f2bf(acc[m][r]);
        }
    }
}

// ---- flash attention: 4 waves (qsub x dhalf), 32 q-rows/wave, KVBLK=32, K+V dbuf ----
// Wave (qsub=w&1, dhalf=w>>1): QK for its 16-key half on 2 q-subtiles; combined max
// via partner exchange (w^2); PV over all 32 keys on its 128-d half. oacc 2x[8].
__global__ __launch_bounds__(256) void attn_k(const unsigned short* __restrict__ qb,
                                              const unsigned short* __restrict__ kb,
                                              const unsigned short* __restrict__ vTb,
                                              unsigned short* __restrict__ ob) {
    __shared__ __attribute__((aligned(16))) char klds[2][32 * 512];           // 32KB swizzled K
    __shared__ __attribute__((aligned(16))) char vlds[2][256 * 64];           // 32KB swizzled V^T
    __shared__ __attribute__((aligned(16))) unsigned int p_lds[2][2][16 * 16];// 4KB P [qsub][sub]
    __shared__ float ex_m[4][32];
    __shared__ float ex_l[4][32];
    const int tid = threadIdx.x;
    const int w = tid >> 6, lane = tid & 63;
    const int c = lane & 15, g = lane >> 4;
    const int qsub = w & 1, dhalf = w >> 1;
    const int khalf = dhalf;
    const int bid = blockIdx.x;
    const int swz = (bid & 7) * 64 + (bid >> 3);  // bijective XCD swizzle (512%8==0)
    const int b = swz >> 5;
    const int qt = swz & 31;
    const int qbase = qt * 64 + qsub * 32;
    constexpr int NT = NN / 32;  // 64 key-tiles

    // staging lane geometry (R4/R8-proven)
    const int sl_sub = lane >> 5;
    const int sl_col = (lane & 31) * 16;
    const int vrow = lane >> 2;
    const int vcol = (((lane & 3) ^ (vrow & 3)) << 4);

    // Q fragments for 2 subtiles (rows qbase..+16, qbase+16..+32)
    const short8* qp0 = (const short8*)(qb + (size_t)(b * NN + qbase + c) * DD + g * 8);
    const short8* qp1 = (const short8*)(qb + (size_t)(b * NN + qbase + 16 + c) * DD + g * 8);
    short8 qf0[8], qf1[8];
#pragma unroll
    for (int kc = 0; kc < 8; kc++) { qf0[kc] = qp0[kc * 4]; qf1[kc] = qp1[kc * 4]; }

    const char* kb_bytes = (const char*)(kb + (size_t)(b * NN) * DD);
    const char* vb_bytes = (const char*)(vTb + (size_t)(b * DD) * NN);
    const int kswz = (c & 7) << 4;
    const int vswz = (c & 3) << 4;
    const int pcs = c & 3;  // P 16B-chunk swizzle

#define STAGE_KV(bufsel, kt_) do {                                                       \
        const char* gk = kb_bytes + ((size_t)((kt_) * 32 + 8 * w)) * 512;                \
        _Pragma("unroll")                                                                \
        for (int s_ = 0; s_ < 4; s_++) {                                                 \
            int row_lo = 2 * s_ + sl_sub;                                                \
            gload_lds16(gk + (size_t)row_lo * 512 + (sl_col ^ (row_lo << 4)),            \
                        &klds[bufsel][0] + (w * 4 + s_) * 1024);                         \
        }                                                                                \
        const char* gv = vb_bytes + ((size_t)(64 * w + vrow) * NN + (kt_) * 32) * 2 + vcol; \
        _Pragma("unroll")                                                                \
        for (int s_ = 0; s_ < 4; s_++) {                                                 \
            gload_lds16(gv + (size_t)(16 * s_) * NN * 2,                                 \
                        &vlds[bufsel][0] + (w * 4 + s_) * 1024);                         \
        }                                                                                \
    } while (0)

    f32x4 oa[8], obc[8];
#pragma unroll
    for (int i = 0; i < 8; i++) { oa[i] = (f32x4){0.f, 0.f, 0.f, 0.f}; obc[i] = (f32x4){0.f, 0.f, 0.f, 0.f}; }
    float mra = -INFINITY, mrb = -INFINITY;
    float lra = 0.f, lrb = 0.f;
    unsigned int* pA = &p_lds[qsub][0][0];
    unsigned int* pB = &p_lds[qsub][1][0];

    STAGE_KV(0, 0);

    for (int kt = 0; kt < NT; kt++) {
        int cur = kt & 1;
        if (kt + 1 < NT) {
            STAGE_KV(cur ^ 1, kt + 1);
            asm volatile("s_waitcnt vmcnt(8)" ::: "memory");
        } else {
            asm volatile("s_waitcnt vmcnt(0)" ::: "memory");
        }
        __builtin_amdgcn_s_barrier();  // B1: tile staged
        fence_mem();

        // ---- swapped QK^T on own 16-key half, both q-subtiles ----
        const char* kl = &klds[cur][0] + (size_t)(khalf * 16) * 512;
        f32x4 sa = (f32x4){0.f, 0.f, 0.f, 0.f};
        f32x4 sb = (f32x4){0.f, 0.f, 0.f, 0.f};
        __builtin_amdgcn_s_setprio(1);
#pragma unroll
        for (int kc = 0; kc < 8; kc++) {
            int col = (kc * 64 + g * 16) ^ kswz;
            short8 kf = *(const short8*)(kl + (size_t)c * 512 + col);
            sa = MFMA16(kf, qf0[kc], sa);
            sb = MFMA16(kf, qf1[kc], sb);
        }
        __builtin_amdgcn_s_setprio(0);

        // ---- own-half row max per subtile, exchange with partner (w^2) ----
        float tma = fmaxf(fmaxf(sa[0], sa[1]), fmaxf(sa[2], sa[3]));
        tma = fmaxf(tma, __shfl_xor(tma, 16));
        tma = fmaxf(tma, __shfl_xor(tma, 32));
        float tmb = fmaxf(fmaxf(sb[0], sb[1]), fmaxf(sb[2], sb[3]));
        tmb = fmaxf(tmb, __shfl_xor(tmb, 16));
        tmb = fmaxf(tmb, __shfl_xor(tmb, 32));
        if (g == 0) { ex_m[w][c] = tma; ex_m[w][16 + c] = tmb; }
        fence_mem();
        __builtin_amdgcn_s_barrier();  // B2: partner max visible
        fence_mem();
        float tmaxa = fmaxf(tma, ex_m[w ^ 2][c]);
        float tmaxb = fmaxf(tmb, ex_m[w ^ 2][16 + c]);

        bool need = (tmaxa > mra + 8.f) || (tmaxb > mrb + 8.f);
        if (__any(need)) {
            float mna = fmaxf(mra, tmaxa);
            float corra = __expf(mra - mna);
#pragma unroll
            for (int r = 0; r < 4; r++) sa[r] = __expf(sa[r] - mna);
            lra = lra * corra + ((sa[0] + sa[1]) + (sa[2] + sa[3]));
            mra = mna;
            float mnb = fmaxf(mrb, tmaxb);
            float corrb = __expf(mrb - mnb);
#pragma unroll
            for (int r = 0; r < 4; r++) sb[r] = __expf(sb[r] - mnb);
            lrb = lrb * corrb + ((sb[0] + sb[1]) + (sb[2] + sb[3]));
            mrb = mnb;
#pragma unroll
            for (int r = 0; r < 4; r++) {
                float cra = __shfl(corra, 20 * g + r);
                float crb = __shfl(corrb, 20 * g + r);
#pragma unroll
                for (int nc = 0; nc < 8; nc++) { oa[nc][r] *= cra; obc[nc][r] *= crb; }
            }
        } else {
#pragma unroll
            for (int r = 0; r < 4; r++) sa[r] = __expf(sa[r] - mra);
            lra += ((sa[0] + sa[1]) + (sa[2] + sa[3]));
#pragma unroll
            for (int r = 0; r < 4; r++) sb[r] = __expf(sb[r] - mrb);
            lrb += ((sb[0] + sb[1]) + (sb[2] + sb[3]));
        }

        // ---- pack own-half P (keys khalf*16 + {4g..4g+3}) for both subtiles ----
        {
            unsigned int pw;
#pragma unroll
            for (int h = 0; h < 2; h++) {
                int j = khalf * 8 + 2 * g + h;
                int pj = (((j >> 2) ^ pcs) << 2) | (j & 3);
                pw = (unsigned int)f2bf(sa[2 * h]) | ((unsigned int)f2bf(sa[2 * h + 1]) << 16);
                pA[c * 16 + pj] = pw;
                pw = (unsigned int)f2bf(sb[2 * h]) | ((unsigned int)f2bf(sb[2 * h + 1]) << 16);
                pB[c * 16 + pj] = pw;
            }
        }
        fence_mem();
        __builtin_amdgcn_s_barrier();  // B3: both halves of P written
        fence_mem();

        // ---- PV: both subtiles x own 128-d half, all 32 keys ----
        short8 pfa = *(const short8*)(pA + c * 16 + ((g ^ pcs) << 2));
        short8 pfb = *(const short8*)(pB + c * 16 + ((g ^ pcs) << 2));
        const char* vl = &vlds[cur][0];
        __builtin_amdgcn_s_setprio(1);
#pragma unroll
        for (int nc = 0; nc < 8; nc++) {
            short8 vf = *(const short8*)(vl + (size_t)(dhalf * 128 + nc * 16 + c) * 64 + ((g * 16) ^ vswz));
            oa[nc] = MFMA16(pfa, vf, oa[nc]);
            obc[nc] = MFMA16(pfb, vf, obc[nc]);
        }
        __builtin_amdgcn_s_setprio(0);

        fence_mem();
        __builtin_amdgcn_s_barrier();  // B4: tile fully consumed (guards stage of kt+2)
        fence_mem();
    }
#undef STAGE_KV

    // ---- epilogue: combine l across dhalf pair, normalize, store ----
    float lta = lra;
    lta += __shfl_xor(lta, 16);
    lta += __shfl_xor(lta, 32);
    float ltb = lrb;
    ltb += __shfl_xor(ltb, 16);
    ltb += __shfl_xor(ltb, 32);
    if (g == 0) { ex_l[w][c] = lta; ex_l[w][16 + c] = ltb; }
    fence_mem();
    __builtin_amdgcn_s_barrier();
    fence_mem();
    lta += ex_l[w ^ 2][c];
    ltb += ex_l[w ^ 2][16 + c];
    float inva[4], invb[4];
#pragma unroll
    for (int r = 0; r < 4; r++) {
        inva[r] = 1.f / __shfl(lta, 20 * g + r);
        invb[r] = 1.f / __shfl(ltb, 20 * g + r);
    }
#pragma unroll
    for (int r = 0; r < 4; r++) {
        size_t ro_a = (size_t)(b * NN + qbase + 4 * g + r) * DD + dhalf * 128;
        size_t ro_b = (size_t)(b * NN + qbase + 16 + 4 * g + r) * DD + dhalf * 128;
#pragma unroll
        for (int nc = 0; nc < 8; nc++) {
            ob[ro_a + nc * 16 + c] = f2bf(oa[nc][r] * inva[r]);
            ob[ro_b + nc * 16 + c] = f2bf(obc[nc][r] * invb[r]);
        }
    }
}

// ---- fused FFN2a + gelu + mean: 1024 blocks, 4 waves (rowgrp x colhalf), acc[8] ----
__global__ __launch_bounds__(256) void out_mean_k(const unsigned short* __restrict__ A,
                                                  const unsigned short* __restrict__ W2aT,
                                                  const float* __restrict__ b2a,
                                                  float* __restrict__ bar) {
    const int w = threadIdx.x >> 6, lane = threadIdx.x & 63;
    const int c = lane & 15, g = lane >> 4;
    const int rb = blockIdx.x * 32 + (w >> 1) * 16;
    const int nh = w & 1;
    const int bb = (blockIdx.x * 32) >> 11;

    const short8* ap = (const short8*)(A + (size_t)(rb + c) * 256 + g * 8);
    f32x4 acc[8];
#pragma unroll
    for (int n = 0; n < 8; n++) acc[n] = (f32x4){0.f, 0.f, 0.f, 0.f};
#pragma unroll
    for (int kc = 0; kc < 8; kc++) {
        short8 a = ap[kc * 4];
#pragma unroll
        for (int n = 0; n < 8; n++) {
            short8 bfr = *(const short8*)(W2aT + (size_t)(nh * 128 + n * 16 + c) * 256 + kc * 32 + g * 8);
            acc[n] = MFMA16(a, bfr, acc[n]);
        }
    }
#pragma unroll
    for (int n = 0; n < 8; n++) {
        int col = nh * 128 + n * 16 + c;
        float bv = b2a[col];
        float s = 0.f;
#pragma unroll
        for (int r = 0; r < 4; r++) s += gelu_exact(acc[n][r] + bv);
        s += __shfl_xor(s, 16);
        s += __shfl_xor(s, 32);
        if (g == 0) atomicAdd(&bar[bb * 256 + col], s);
    }
}

// ---- final projection ----
__global__ void final_k(const float* __restrict__ bar, const float* __restrict__ W2b,
                        const float* __restrict__ b2b, float* __restrict__ out) {
    int b = blockIdx.x, d = threadIdx.x;
    float s = 0.f;
    for (int h = 0; h < HH; h++) s += bar[b * HH + h] * W2b[h * DD + d];
    out[b * DD + d] = b2b[d] + s * (1.f / (float)NN);
}

extern "C" void kernel_launch(void* const* d_in, const int* in_sizes, int n_in,
                              void* d_out, int out_size, void* d_ws, size_t ws_size,
                              hipStream_t stream) {
    (void)in_sizes; (void)n_in; (void)out_size; (void)ws_size;
    const float* x    = (const float*)d_in[0];
    const float* grd  = (const float*)d_in[1];
    const float* W1a  = (const float*)d_in[2];
    const float* b1a  = (const float*)d_in[3];
    const float* W1b  = (const float*)d_in[4];
    const float* b1b  = (const float*)d_in[5];
    const float* Wqkv = (const float*)d_in[6];
    const float* W2a  = (const float*)d_in[7];
    const float* b2a  = (const float*)d_in[8];
    const float* W2b  = (const float*)d_in[9];
    const float* b2b  = (const float*)d_in[10];
    float* out = (float*)d_out;

    char* ws = (char*)d_ws;
    const size_t MB = 1024 * 1024;
    unsigned short* q_buf  = (unsigned short*)(ws + 0);
    unsigned short* k_buf  = (unsigned short*)(ws + 16 * MB);
    unsigned short* vT_buf = (unsigned short*)(ws + 32 * MB);
    unsigned short* o_buf  = (unsigned short*)(ws + 48 * MB);
    unsigned short* W1bT   = (unsigned short*)(ws + 80 * MB);
    unsigned short* WqkvT  = (unsigned short*)(ws + 80 * MB + 512 * 1024);
    unsigned short* W2aT   = (unsigned short*)(ws + 81 * MB);
    float*          bar    = (float*)(ws + 81 * MB + 256 * 1024);

    transposeT_k<<<dim3(80), 256, 0, stream>>>(W1b, Wqkv, W2a, W1bT, WqkvT, W2aT);
    ffn_qkv_k<<<dim3(512), 512, 0, stream>>>(x, grd, W1a, b1a, W1bT, b1b, WqkvT,
                                             q_buf, k_buf, vT_buf);
    attn_k<<<dim3(512), 256, 0, stream>>>(q_buf, k_buf, vT_buf, o_buf);
    hipMemsetAsync(bar, 0, BB * HH * sizeof(float), stream);
    out_mean_k<<<dim3(1024), 256, 0, stream>>>(o_buf, W2aT, b2a, bar);
    final_k<<<dim3(BB), 256, 0, stream>>>(bar, W2b, b2b, out);
}

// Round 12
// 324.398 us; speedup vs baseline: 1.3597x; 1.3597x over previous
//
#include <hip/hip_runtime.h>
#include <hip/hip_bf16.h>
#include <cmath>

typedef __attribute__((ext_vector_type(8))) short short8;
typedef __attribute__((ext_vector_type(4))) float f32x4;

#define MFMA16(a, b, c) __builtin_amdgcn_mfma_f32_16x16x32_bf16((a), (b), (c), 0, 0, 0)

static constexpr int BB = 16, NN = 2048, DD = 256, HH = 256;

__device__ inline unsigned short f2bf(float f) {
    union { float f; unsigned int u; } v; v.f = f;
    unsigned int r = v.u + 0x7fffu + ((v.u >> 16) & 1u);
    return (unsigned short)(r >> 16);
}
__device__ inline float bf2f(unsigned short u) {
    union { unsigned int u; float f; } v; v.u = ((unsigned int)u) << 16;
    return v.f;
}
__device__ inline float gelu_exact(float x) {
    return 0.5f * x * (1.0f + erff(x * 0.7071067811865475f));
}
__device__ inline void gload_lds16(const void* g, void* l) {
    __builtin_amdgcn_global_load_lds(
        (const __attribute__((address_space(1))) unsigned int*)g,
        (__attribute__((address_space(3))) unsigned int*)l, 16, 0, 0);
}
__device__ inline void fence_mem() { asm volatile("" ::: "memory"); }

// ---- tiled weight transpose: fp32 [256][N] -> bf16 [N][256], coalesced ----
__global__ __launch_bounds__(256) void transposeT_k(const float* __restrict__ W1b,
                                                    const float* __restrict__ Wqkv,
                                                    const float* __restrict__ W2a,
                                                    unsigned short* __restrict__ W1bT,
                                                    unsigned short* __restrict__ WqkvT,
                                                    unsigned short* __restrict__ W2aT) {
    __shared__ float tl[64][65];
    int bid = blockIdx.x;  // 80 blocks: 16 W1b, 48 Wqkv, 16 W2a
    const float* src;
    unsigned short* dst;
    int N, tn, tk;
    if (bid < 16) {
        src = W1b; dst = W1bT; N = 256; tn = bid & 3; tk = bid >> 2;
    } else if (bid < 64) {
        int t2 = bid - 16;
        src = Wqkv; dst = WqkvT; N = 768; tn = t2 % 12; tk = t2 / 12;
    } else {
        int t2 = bid - 64;
        src = W2a; dst = W2aT; N = 256; tn = t2 & 3; tk = t2 >> 2;
    }
    int n0 = tn * 64, k0 = tk * 64;
    int t = threadIdx.x;
#pragma unroll
    for (int j = 0; j < 4; j++) {
        int row = (t >> 4) * 4 + j;
        f32x4 v = *(const f32x4*)(src + (size_t)(k0 + row) * N + n0 + (t & 15) * 4);
#pragma unroll
        for (int e = 0; e < 4; e++) tl[row][(t & 15) * 4 + e] = v[e];
    }
    __syncthreads();
    int n = t >> 2, cb = (t & 3) * 16;
    short8 a, b;
#pragma unroll
    for (int e = 0; e < 8; e++) {
        a[e] = (short)f2bf(tl[cb + e][n]);
        b[e] = (short)f2bf(tl[cb + 8 + e][n]);
    }
    *(short8*)(dst + (size_t)(n0 + n) * 256 + k0 + cb) = a;
    *(short8*)(dst + (size_t)(n0 + n) * 256 + k0 + cb + 8) = b;
}

// ---- fused FFN1 + qkv, 8 waves: (qsub = w>>1, nhalf = w&1), acc[8] ----
__global__ __launch_bounds__(512) void ffn_qkv_k(const float* __restrict__ x,
                                                 const float* __restrict__ grd,
                                                 const float* __restrict__ W1a,
                                                 const float* __restrict__ b1a,
                                                 const unsigned short* __restrict__ W1bT,
                                                 const float* __restrict__ b1b,
                                                 const unsigned short* __restrict__ WqkvT,
                                                 unsigned short* __restrict__ qo,
                                                 unsigned short* __restrict__ ko,
                                                 unsigned short* __restrict__ vo) {
    __shared__ unsigned short h_lds[4][16 * 256];  // per qsub, written by both nhalves
    const int w = threadIdx.x >> 6, lane = threadIdx.x & 63;
    const int c = lane & 15, g = lane >> 4;
    const int qsub = w >> 1, nh = w & 1;
    const int rb = blockIdx.x * 64 + qsub * 16;
    const int bb = (blockIdx.x * 64) >> 11;
    const int rowinb = (rb & (NN - 1)) + c;

    const int p = rb + c;
    const float xv = x[p];
    const float gv = grd[p & (NN - 1)];
    short8 tf[8];
#pragma unroll
    for (int kc = 0; kc < 8; kc++) {
        int j0 = kc * 32 + g * 8;
#pragma unroll
        for (int e = 0; e < 8; e += 4) {
            f32x4 wa = *(const f32x4*)(W1a + j0 + e);
            f32x4 wb = *(const f32x4*)(W1a + 256 + j0 + e);
            f32x4 ba = *(const f32x4*)(b1a + j0 + e);
#pragma unroll
            for (int q = 0; q < 4; q++) {
                float v = xv * wa[q] + gv * wb[q] + ba[q];
                tf[kc][e + q] = (short)f2bf(gelu_exact(v));
            }
        }
    }

    f32x4 acc[8];
#pragma unroll
    for (int n = 0; n < 8; n++) acc[n] = (f32x4){0.f, 0.f, 0.f, 0.f};
#pragma unroll
    for (int kc = 0; kc < 8; kc++) {
        short8 a = tf[kc];
#pragma unroll
        for (int n = 0; n < 8; n++) {
            short8 bfr = *(const short8*)(W1bT + (size_t)(nh * 128 + n * 16 + c) * 256 + kc * 32 + g * 8);
            acc[n] = MFMA16(a, bfr, acc[n]);
        }
    }
    unsigned short* hl = &h_lds[qsub][0];
#pragma unroll
    for (int n = 0; n < 8; n++) {
        int col = nh * 128 + n * 16 + c;
        float bv = b1b[col];
#pragma unroll
        for (int r = 0; r < 4; r++) {
            int row = g * 4 + r;
            hl[row * 256 + (col ^ ((row & 7) << 3))] = f2bf(acc[n][r] + bv);
        }
    }
    __syncthreads();
    short8 hf[8];
#pragma unroll
    for (int kc = 0; kc < 8; kc++) {
        hf[kc] = *(const short8*)(hl + c * 256 + ((kc * 32 + g * 8) ^ ((c & 7) << 3)));
    }

    // q (scaled 1/16), own col-half
#pragma unroll
    for (int n = 0; n < 8; n++) acc[n] = (f32x4){0.f, 0.f, 0.f, 0.f};
#pragma unroll
    for (int kc = 0; kc < 8; kc++) {
        short8 a = hf[kc];
#pragma unroll
        for (int n = 0; n < 8; n++) {
            short8 bfr = *(const short8*)(WqkvT + (size_t)(nh * 128 + n * 16 + c) * 256 + kc * 32 + g * 8);
            acc[n] = MFMA16(a, bfr, acc[n]);
        }
    }
#pragma unroll
    for (int n = 0; n < 8; n++)
#pragma unroll
        for (int r = 0; r < 4; r++)
            qo[(size_t)(rb + g * 4 + r) * 256 + nh * 128 + n * 16 + c] = f2bf(acc[n][r] * 0.0625f);

    // k
#pragma unroll
    for (int n = 0; n < 8; n++) acc[n] = (f32x4){0.f, 0.f, 0.f, 0.f};
#pragma unroll
    for (int kc = 0; kc < 8; kc++) {
        short8 a = hf[kc];
#pragma unroll
        for (int n = 0; n < 8; n++) {
            short8 bfr = *(const short8*)(WqkvT + (size_t)(256 + nh * 128 + n * 16 + c) * 256 + kc * 32 + g * 8);
            acc[n] = MFMA16(a, bfr, acc[n]);
        }
    }
#pragma unroll
    for (int n = 0; n < 8; n++)
#pragma unroll
        for (int r = 0; r < 4; r++)
            ko[(size_t)(rb + g * 4 + r) * 256 + nh * 128 + n * 16 + c] = f2bf(acc[n][r]);

    // v (swapped operands -> v^T), own d-half
#pragma unroll
    for (int m = 0; m < 8; m++) acc[m] = (f32x4){0.f, 0.f, 0.f, 0.f};
#pragma unroll
    for (int kc = 0; kc < 8; kc++) {
        short8 b = hf[kc];
#pragma unroll
        for (int m = 0; m < 8; m++) {
            short8 afr = *(const short8*)(WqkvT + (size_t)(512 + nh * 128 + m * 16 + c) * 256 + kc * 32 + g * 8);
            acc[m] = MFMA16(afr, b, acc[m]);
        }
    }
#pragma unroll
    for (int m = 0; m < 8; m++) {
#pragma unroll
        for (int r = 0; r < 4; r++) {
            int dcol = nh * 128 + m * 16 + g * 4 + r;
            vo[((size_t)(bb * 256 + dcol)) * NN + rowinb] = f2bf(acc[m][r]);
        }
    }
}

// ---- flash attention (R10 structure) + fused FFN2a/gelu/mean epilogue ----
// Main loop: 8 waves (qsub=w&3, dhalf=w>>2), KVBLK=64 single-buffer, oacc[8].
// Epilogue: o-tile (64q x 256d) into reused LDS, GEMM @W2aT + gelu + rowsum -> bar.
__global__ __launch_bounds__(512) void attn_k(const unsigned short* __restrict__ qb,
                                              const unsigned short* __restrict__ kb,
                                              const unsigned short* __restrict__ vTb,
                                              const unsigned short* __restrict__ W2aT,
                                              const float* __restrict__ b2a,
                                              float* __restrict__ bar) {
    __shared__ __attribute__((aligned(16))) char smem[64 * 512 + 256 * 128 + 8192 + 1024];
    char* klds = smem;                                           // 32KB swizzled K
    char* vlds = smem + 32768;                                   // 32KB swizzled V^T
    unsigned int* p_lds = (unsigned int*)(smem + 65536);         // 8KB: [qsub][16*32]
    float* exm = (float*)(smem + 65536 + 8192);                  // [8][16]
    float* exl = exm + 128;                                      // [8][16]
    const int tid = threadIdx.x;
    const int w = tid >> 6, lane = tid & 63;
    const int c = lane & 15, g = lane >> 4;
    const int qsub = w & 3, dhalf = w >> 2;
    const int khalf = dhalf;
    const int bid = blockIdx.x;
    const int swz = (bid & 7) * 64 + (bid >> 3);  // bijective XCD swizzle (512%8==0)
    const int b = swz >> 5;
    const int qt = swz & 31;
    const int qbase = qt * 64 + qsub * 16;
    constexpr int NT = NN / 64;  // 32 key-tiles

    const int sl_sub = lane >> 5;
    const int sl_col = (lane & 31) * 16;
    const int vl_row = lane >> 3;
    const size_t vl_off = (size_t)vl_row * (NN * 2) + (size_t)(((lane & 7) ^ vl_row) << 4);

    const short8* qp = (const short8*)(qb + (size_t)(b * NN + qbase + c) * DD + g * 8);
    short8 qf[8];
#pragma unroll
    for (int kc = 0; kc < 8; kc++) qf[kc] = qp[kc * 4];

    const char* kb_bytes = (const char*)(kb + (size_t)(b * NN) * DD);
    const char* vb_bytes = (const char*)(vTb + (size_t)(b * DD) * NN);
    const int kswz = (c & 7) << 4;
    const int pcs = c & 7;

#define STAGE_KV(kt_) do {                                                               \
        const char* gk = kb_bytes + ((size_t)((kt_) * 64 + 8 * w)) * 512;                \
        _Pragma("unroll")                                                                \
        for (int s_ = 0; s_ < 4; s_++) {                                                 \
            int row_lo = 2 * s_ + sl_sub;                                                \
            gload_lds16(gk + (size_t)row_lo * 512 + (sl_col ^ (row_lo << 4)),            \
                        klds + (8 * w + 2 * s_) * 512);                                  \
        }                                                                                \
        const char* gv = vb_bytes + (size_t)(32 * w) * (NN * 2) + (size_t)(kt_) * 128 + vl_off; \
        _Pragma("unroll")                                                                \
        for (int s_ = 0; s_ < 4; s_++) {                                                 \
            gload_lds16(gv + (size_t)(8 * s_) * (NN * 2),                                \
                        vlds + (32 * w + 8 * s_) * 128);                                 \
        }                                                                                \
    } while (0)

    f32x4 oacc[8];
#pragma unroll
    for (int i = 0; i < 8; i++) oacc[i] = (f32x4){0.f, 0.f, 0.f, 0.f};
    float mrun = -INFINITY;
    float lrun = 0.f;
    unsigned int* plw = p_lds + qsub * 512 + c * 32;

    for (int kt = 0; kt < NT; kt++) {
        STAGE_KV(kt);
        asm volatile("s_waitcnt vmcnt(0)" ::: "memory");
        __builtin_amdgcn_s_barrier();  // B1: K+V tile staged
        fence_mem();

        const char* klb = klds + (size_t)(khalf * 32) * 512;
        f32x4 s0 = (f32x4){0.f, 0.f, 0.f, 0.f};
        f32x4 s1 = (f32x4){0.f, 0.f, 0.f, 0.f};
        __builtin_amdgcn_s_setprio(1);
#pragma unroll
        for (int kc = 0; kc < 8; kc++) {
            short8 qv = qf[kc];
            int col = (kc * 64 + g * 16) ^ kswz;
            short8 kf0 = *(const short8*)(klb + (size_t)c * 512 + col);
            short8 kf1 = *(const short8*)(klb + (size_t)(c + 16) * 512 + col);
            s0 = MFMA16(kf0, qv, s0);
            s1 = MFMA16(kf1, qv, s1);
        }
        __builtin_amdgcn_s_setprio(0);

        float t0 = fmaxf(fmaxf(s0[0], s0[1]), fmaxf(s0[2], s0[3]));
        float t1 = fmaxf(fmaxf(s1[0], s1[1]), fmaxf(s1[2], s1[3]));
        float tmo = fmaxf(t0, t1);
        tmo = fmaxf(tmo, __shfl_xor(tmo, 16));
        tmo = fmaxf(tmo, __shfl_xor(tmo, 32));
        if (g == 0) exm[w * 16 + c] = tmo;
        fence_mem();
        __builtin_amdgcn_s_barrier();  // B2: partner max visible
        fence_mem();
        float tmax = fmaxf(tmo, exm[(w ^ 4) * 16 + c]);

        bool need = tmax > mrun + 8.f;
        if (__any(need)) {
            float mn = fmaxf(mrun, tmax);
            float corr = __expf(mrun - mn);
#pragma unroll
            for (int r = 0; r < 4; r++) s0[r] = __expf(s0[r] - mn);
#pragma unroll
            for (int r = 0; r < 4; r++) s1[r] = __expf(s1[r] - mn);
            lrun = lrun * corr + ((s0[0] + s0[1]) + (s0[2] + s0[3])) +
                   ((s1[0] + s1[1]) + (s1[2] + s1[3]));
            mrun = mn;
#pragma unroll
            for (int r = 0; r < 4; r++) {
                float cr = __shfl(corr, 20 * g + r);
#pragma unroll
                for (int nc = 0; nc < 8; nc++) oacc[nc][r] *= cr;
            }
        } else {
#pragma unroll
            for (int r = 0; r < 4; r++) s0[r] = __expf(s0[r] - mrun);
#pragma unroll
            for (int r = 0; r < 4; r++) s1[r] = __expf(s1[r] - mrun);
            lrun += ((s0[0] + s0[1]) + (s0[2] + s0[3])) +
                    ((s1[0] + s1[1]) + (s1[2] + s1[3]));
        }

        {
            int jb0 = khalf * 16 + 2 * g;
            int jb1 = khalf * 16 + 8 + 2 * g;
            unsigned int pw;
#pragma unroll
            for (int h = 0; h < 2; h++) {
                int j = jb0 + h;
                pw = (unsigned int)f2bf(s0[2 * h]) | ((unsigned int)f2bf(s0[2 * h + 1]) << 16);
                plw[(((j >> 2) ^ pcs) << 2) | (j & 3)] = pw;
                j = jb1 + h;
                pw = (unsigned int)f2bf(s1[2 * h]) | ((unsigned int)f2bf(s1[2 * h + 1]) << 16);
                plw[(((j >> 2) ^ pcs) << 2) | (j & 3)] = pw;
            }
        }
        fence_mem();
        __builtin_amdgcn_s_barrier();  // B3: both P halves of every qsub written
        fence_mem();

        short8 pf0 = *(const short8*)(plw + ((g ^ pcs) << 2));
        short8 pf1 = *(const short8*)(plw + (((4 + g) ^ pcs) << 2));
        __builtin_amdgcn_s_setprio(1);
#pragma unroll
        for (int nc = 0; nc < 8; nc++) {
            const char* vr = vlds + (size_t)(dhalf * 128 + nc * 16 + c) * 128;
            short8 vf0 = *(const short8*)(vr + ((g ^ pcs) << 4));
            short8 vf1 = *(const short8*)(vr + (((4 + g) ^ pcs) << 4));
            oacc[nc] = MFMA16(pf0, vf0, oacc[nc]);
            oacc[nc] = MFMA16(pf1, vf1, oacc[nc]);
        }
        __builtin_amdgcn_s_setprio(0);

        fence_mem();
        __builtin_amdgcn_s_barrier();  // B4: tile fully consumed
        fence_mem();
    }
#undef STAGE_KV

    // ---- combine l across pair ----
    float lt = lrun;
    lt += __shfl_xor(lt, 16);
    lt += __shfl_xor(lt, 32);
    if (g == 0) exl[w * 16 + c] = lt;
    fence_mem();
    __builtin_amdgcn_s_barrier();
    fence_mem();
    lt += exl[(w ^ 4) * 16 + c];
    float inv_r[4];
#pragma unroll
    for (int r = 0; r < 4; r++) inv_r[r] = 1.f / __shfl(lt, 20 * g + r);

    // ---- write normalized o-tile into reused LDS (klds+vlds region, 32KB used) ----
    // layout: [qsub][row16][256 cols], col XOR-swizzled by (row&7)<<3 (h_lds pattern)
    unsigned short* ol = (unsigned short*)smem;
#pragma unroll
    for (int r = 0; r < 4; r++) {
        int row = 4 * g + r;
        int swr = (row & 7) << 3;
#pragma unroll
        for (int nc = 0; nc < 8; nc++) {
            int col = dhalf * 128 + nc * 16 + c;
            ol[qsub * 4096 + row * 256 + (col ^ swr)] = f2bf(oacc[nc][r] * inv_r[r]);
        }
    }
    fence_mem();
    __builtin_amdgcn_s_barrier();  // o-tile complete
    fence_mem();

    // ---- fused FFN2a + gelu + mean: wave w owns output cols [32w, 32w+32) ----
    {
        const int wcol = w * 32;
        float colsum[2] = {0.f, 0.f};
#pragma unroll
        for (int q2 = 0; q2 < 4; q2++) {
            f32x4 acc2[2];
            acc2[0] = (f32x4){0.f, 0.f, 0.f, 0.f};
            acc2[1] = (f32x4){0.f, 0.f, 0.f, 0.f};
            const unsigned short* oq = ol + q2 * 4096;
            const int swc = (c & 7) << 3;
#pragma unroll
            for (int kc = 0; kc < 8; kc++) {
                short8 a = *(const short8*)(oq + c * 256 + ((kc * 32 + g * 8) ^ swc));
#pragma unroll
                for (int nc = 0; nc < 2; nc++) {
                    short8 bfr = *(const short8*)(W2aT + (size_t)(wcol + nc * 16 + c) * 256 + kc * 32 + g * 8);
                    acc2[nc] = MFMA16(a, bfr, acc2[nc]);
                }
            }
#pragma unroll
            for (int nc = 0; nc < 2; nc++) {
                float bv = b2a[wcol + nc * 16 + c];
                float s = 0.f;
#pragma unroll
                for (int r = 0; r < 4; r++) s += gelu_exact(acc2[nc][r] + bv);
                colsum[nc] += s;
            }
        }
#pragma unroll
        for (int nc = 0; nc < 2; nc++) {
            float s = colsum[nc];
            s += __shfl_xor(s, 16);
            s += __shfl_xor(s, 32);
            if (g == 0) atomicAdd(&bar[b * 256 + wcol + nc * 16 + c], s);
        }
    }
}

// ---- final projection ----
__global__ void final_k(const float* __restrict__ bar, const float* __restrict__ W2b,
                        const float* __restrict__ b2b, float* __restrict__ out) {
    int b = blockIdx.x, d = threadIdx.x;
    float s = 0.f;
    for (int h = 0; h < HH; h++) s += bar[b * HH + h] * W2b[h * DD + d];
    out[b * DD + d] = b2b[d] + s * (1.f / (float)NN);
}

extern "C" void kernel_launch(void* const* d_in, const int* in_sizes, int n_in,
                              void* d_out, int out_size, void* d_ws, size_t ws_size,
                              hipStream_t stream) {
    (void)in_sizes; (void)n_in; (void)out_size; (void)ws_size;
    const float* x    = (const float*)d_in[0];
    const float* grd  = (const float*)d_in[1];
    const float* W1a  = (const float*)d_in[2];
    const float* b1a  = (const float*)d_in[3];
    const float* W1b  = (const float*)d_in[4];
    const float* b1b  = (const float*)d_in[5];
    const float* Wqkv = (const float*)d_in[6];
    const float* W2a  = (const float*)d_in[7];
    const float* b2a  = (const float*)d_in[8];
    const float* W2b  = (const float*)d_in[9];
    const float* b2b  = (const float*)d_in[10];
    float* out = (float*)d_out;

    char* ws = (char*)d_ws;
    const size_t MB = 1024 * 1024;
    unsigned short* q_buf  = (unsigned short*)(ws + 0);
    unsigned short* k_buf  = (unsigned short*)(ws + 16 * MB);
    unsigned short* vT_buf = (unsigned short*)(ws + 32 * MB);
    unsigned short* W1bT   = (unsigned short*)(ws + 80 * MB);
    unsigned short* WqkvT  = (unsigned short*)(ws + 80 * MB + 512 * 1024);
    unsigned short* W2aT   = (unsigned short*)(ws + 81 * MB);
    float*          bar    = (float*)(ws + 81 * MB + 256 * 1024);

    transposeT_k<<<dim3(80), 256, 0, stream>>>(W1b, Wqkv, W2a, W1bT, WqkvT, W2aT);
    ffn_qkv_k<<<dim3(512), 512, 0, stream>>>(x, grd, W1a, b1a, W1bT, b1b, WqkvT,
                                             q_buf, k_buf, vT_buf);
    hipMemsetAsync(bar, 0, BB * HH * sizeof(float), stream);
    attn_k<<<dim3(512), 512, 0, stream>>>(q_buf, k_buf, vT_buf, W2aT, b2a, bar);
    final_k<<<dim3(BB), 256, 0, stream>>>(bar, W2b, b2b, out);
}

// Round 13
// 239.397 us; speedup vs baseline: 1.8425x; 1.3551x over previous
//
#include <hip/hip_runtime.h>
#include <hip/hip_bf16.h>
#include <cmath>

typedef __attribute__((ext_vector_type(8))) short short8;
typedef __attribute__((ext_vector_type(4))) float f32x4;

#define MFMA16(a, b, c) __builtin_amdgcn_mfma_f32_16x16x32_bf16((a), (b), (c), 0, 0, 0)

static constexpr int BB = 16, NN = 2048, DD = 256, HH = 256;

__device__ inline unsigned short f2bf(float f) {
    union { float f; unsigned int u; } v; v.f = f;
    unsigned int r = v.u + 0x7fffu + ((v.u >> 16) & 1u);
    return (unsigned short)(r >> 16);
}
__device__ inline float bf2f(unsigned short u) {
    union { unsigned int u; float f; } v; v.u = ((unsigned int)u) << 16;
    return v.f;
}
__device__ inline float gelu_exact(float x) {
    return 0.5f * x * (1.0f + erff(x * 0.7071067811865475f));
}
__device__ inline void gload_lds16(const void* g, void* l) {
    __builtin_amdgcn_global_load_lds(
        (const __attribute__((address_space(1))) unsigned int*)g,
        (__attribute__((address_space(3))) unsigned int*)l, 16, 0, 0);
}
__device__ inline void fence_mem() { asm volatile("" ::: "memory"); }

// ---- tiled weight transpose: fp32 [256][N] -> bf16 [N][256], coalesced ----
__global__ __launch_bounds__(256) void transposeT_k(const float* __restrict__ W1b,
                                                    const float* __restrict__ Wqkv,
                                                    const float* __restrict__ W2a,
                                                    unsigned short* __restrict__ W1bT,
                                                    unsigned short* __restrict__ WqkvT,
                                                    unsigned short* __restrict__ W2aT) {
    __shared__ float tl[64][65];
    int bid = blockIdx.x;  // 80 blocks: 16 W1b, 48 Wqkv, 16 W2a
    const float* src;
    unsigned short* dst;
    int N, tn, tk;
    if (bid < 16) {
        src = W1b; dst = W1bT; N = 256; tn = bid & 3; tk = bid >> 2;
    } else if (bid < 64) {
        int t2 = bid - 16;
        src = Wqkv; dst = WqkvT; N = 768; tn = t2 % 12; tk = t2 / 12;
    } else {
        int t2 = bid - 64;
        src = W2a; dst = W2aT; N = 256; tn = t2 & 3; tk = t2 >> 2;
    }
    int n0 = tn * 64, k0 = tk * 64;
    int t = threadIdx.x;
#pragma unroll
    for (int j = 0; j < 4; j++) {
        int row = (t >> 4) * 4 + j;
        f32x4 v = *(const f32x4*)(src + (size_t)(k0 + row) * N + n0 + (t & 15) * 4);
#pragma unroll
        for (int e = 0; e < 4; e++) tl[row][(t & 15) * 4 + e] = v[e];
    }
    __syncthreads();
    int n = t >> 2, cb = (t & 3) * 16;
    short8 a, b;
#pragma unroll
    for (int e = 0; e < 8; e++) {
        a[e] = (short)f2bf(tl[cb + e][n]);
        b[e] = (short)f2bf(tl[cb + 8 + e][n]);
    }
    *(short8*)(dst + (size_t)(n0 + n) * 256 + k0 + cb) = a;
    *(short8*)(dst + (size_t)(n0 + n) * 256 + k0 + cb + 8) = b;
}

// ---- fused FFN1 + qkv, 8 waves (qsub = w>>1, nhalf = w&1), acc[8] ----
// Weights staged into LDS in 32KB kc-pair chunks, double-buffered, counted vmcnt.
__global__ __launch_bounds__(512) void ffn_qkv_k(const float* __restrict__ x,
                                                 const float* __restrict__ grd,
                                                 const float* __restrict__ W1a,
                                                 const float* __restrict__ b1a,
                                                 const unsigned short* __restrict__ W1bT,
                                                 const float* __restrict__ b1b,
                                                 const unsigned short* __restrict__ WqkvT,
                                                 unsigned short* __restrict__ qo,
                                                 unsigned short* __restrict__ ko,
                                                 unsigned short* __restrict__ vo) {
    __shared__ __attribute__((aligned(16))) char bstage[2][32768];  // 64KB weight dbuf
    __shared__ unsigned short h_lds[4][16 * 256];                   // 16KB (total 80KB)
    const int w = threadIdx.x >> 6, lane = threadIdx.x & 63;
    const int c = lane & 15, g = lane >> 4;
    const int qsub = w >> 1, nh = w & 1;
    const int rb = blockIdx.x * 64 + qsub * 16;
    const int bb = (blockIdx.x * 64) >> 11;
    const int rowinb = (rb & (NN - 1)) + c;

    // ---- t A-fragments inline (row rb+c, cols kc*32+g*8..+7) ----
    const int p0r = rb + c;
    const float xv = x[p0r];
    const float gv = grd[p0r & (NN - 1)];
    short8 tf[8];
#pragma unroll
    for (int kc = 0; kc < 8; kc++) {
        int j0 = kc * 32 + g * 8;
#pragma unroll
        for (int e = 0; e < 8; e += 4) {
            f32x4 wa = *(const f32x4*)(W1a + j0 + e);
            f32x4 wb = *(const f32x4*)(W1a + 256 + j0 + e);
            f32x4 ba = *(const f32x4*)(b1a + j0 + e);
#pragma unroll
            for (int q = 0; q < 4; q++) {
                float v = xv * wa[q] + gv * wb[q] + ba[q];
                tf[kc][e + q] = (short)f2bf(gelu_exact(v));
            }
        }
    }

    // Bbase per pass (byte pointers; rows are 512B = 256 cols x 2B)
    const char* Bb0 = (const char*)W1bT;
    const char* Bb1 = (const char*)WqkvT;
    const char* Bb2 = (const char*)WqkvT + 256 * 512;
    const char* Bb3 = (const char*)WqkvT + 512 * 512;

    // stage chunk (p,kcp): all 256 rows, bytes [kcp*128, +128), slot pre-swizzled
#define STAGE_B(buf_, Bb_, kcp_) do {                                                    \
        _Pragma("unroll")                                                                \
        for (int i_ = 0; i_ < 4; i_++) {                                                 \
            int d_ = i_ * 8192 + w * 1024 + lane * 16;                                   \
            int row_ = d_ >> 7, sl_ = (d_ >> 4) & 7;                                     \
            gload_lds16(Bb_ + (size_t)row_ * 512 + (kcp_) * 128 +                        \
                            ((sl_ ^ (row_ & 7)) << 4),                                   \
                        &bstage[buf_][0] + d_);                                          \
        }                                                                                \
    } while (0)

    short8 hf[8];
#pragma unroll
    for (int kc = 0; kc < 8; kc++) hf[kc] = tf[kc];  // placeholder init (overwritten after p0)

    STAGE_B(0, Bb0, 0);  // prologue: chunk gi=0

#pragma unroll
    for (int p = 0; p < 4; p++) {
        f32x4 acc[8];
#pragma unroll
        for (int n = 0; n < 8; n++) acc[n] = (f32x4){0.f, 0.f, 0.f, 0.f};

#pragma unroll
        for (int kcp = 0; kcp < 4; kcp++) {
            const int gi = p * 4 + kcp;
            if (gi + 1 < 16) {
                const int ni = gi + 1;
                const char* nb = (ni >> 2) == 0 ? Bb0 : (ni >> 2) == 1 ? Bb1
                                : (ni >> 2) == 2 ? Bb2 : Bb3;
                STAGE_B(ni & 1, nb, ni & 3);
                asm volatile("s_waitcnt vmcnt(4)" ::: "memory");
            } else {
                asm volatile("s_waitcnt vmcnt(0)" ::: "memory");
            }
            __builtin_amdgcn_s_barrier();  // B1: chunk gi staged
            fence_mem();

            const char* bl = &bstage[gi & 1][0];
#pragma unroll
            for (int sub = 0; sub < 2; sub++) {
                short8 a = (p == 0) ? tf[kcp * 2 + sub] : hf[kcp * 2 + sub];
#pragma unroll
                for (int n = 0; n < 8; n++) {
                    int addr = (nh * 128 + n * 16 + c) * 128 +
                               ((((sub << 2) | g) ^ (c & 7)) << 4);
                    short8 bfr = *(const short8*)(bl + addr);
                    if (p == 3) acc[n] = MFMA16(bfr, a, acc[n]);  // swapped: v^T
                    else        acc[n] = MFMA16(a, bfr, acc[n]);
                }
            }
            fence_mem();
            __builtin_amdgcn_s_barrier();  // B2: chunk gi consumed
            fence_mem();
        }

        if (p == 0) {
            // h -> per-qsub LDS (+bias), sync, read back full-row fragments
            unsigned short* hl = &h_lds[qsub][0];
#pragma unroll
            for (int n = 0; n < 8; n++) {
                int col = nh * 128 + n * 16 + c;
                float bv = b1b[col];
#pragma unroll
                for (int r = 0; r < 4; r++) {
                    int row = g * 4 + r;
                    hl[row * 256 + (col ^ ((row & 7) << 3))] = f2bf(acc[n][r] + bv);
                }
            }
            __syncthreads();
#pragma unroll
            for (int kc = 0; kc < 8; kc++) {
                hf[kc] = *(const short8*)(hl + c * 256 + ((kc * 32 + g * 8) ^ ((c & 7) << 3)));
            }
        } else if (p == 1) {
#pragma unroll
            for (int n = 0; n < 8; n++)
#pragma unroll
                for (int r = 0; r < 4; r++)
                    qo[(size_t)(rb + g * 4 + r) * 256 + nh * 128 + n * 16 + c] =
                        f2bf(acc[n][r] * 0.0625f);
        } else if (p == 2) {
#pragma unroll
            for (int n = 0; n < 8; n++)
#pragma unroll
                for (int r = 0; r < 4; r++)
                    ko[(size_t)(rb + g * 4 + r) * 256 + nh * 128 + n * 16 + c] =
                        f2bf(acc[n][r]);
        } else {
#pragma unroll
            for (int m = 0; m < 8; m++) {
#pragma unroll
                for (int r = 0; r < 4; r++) {
                    int dcol = nh * 128 + m * 16 + g * 4 + r;
                    vo[((size_t)(bb * 256 + dcol)) * NN + rowinb] = f2bf(acc[m][r]);
                }
            }
        }
    }
#undef STAGE_B
}

// ---- flash attention (R10 structure) + fused FFN2a/gelu/mean epilogue ----
__global__ __launch_bounds__(512) void attn_k(const unsigned short* __restrict__ qb,
                                              const unsigned short* __restrict__ kb,
                                              const unsigned short* __restrict__ vTb,
                                              const unsigned short* __restrict__ W2aT,
                                              const float* __restrict__ b2a,
                                              float* __restrict__ bar) {
    __shared__ __attribute__((aligned(16))) char smem[64 * 512 + 256 * 128 + 8192 + 1024];
    char* klds = smem;                                           // 32KB swizzled K
    char* vlds = smem + 32768;                                   // 32KB swizzled V^T
    unsigned int* p_lds = (unsigned int*)(smem + 65536);         // 8KB: [qsub][16*32]
    float* exm = (float*)(smem + 65536 + 8192);                  // [8][16]
    float* exl = exm + 128;                                      // [8][16]
    const int tid = threadIdx.x;
    const int w = tid >> 6, lane = tid & 63;
    const int c = lane & 15, g = lane >> 4;
    const int qsub = w & 3, dhalf = w >> 2;
    const int khalf = dhalf;
    const int bid = blockIdx.x;
    const int swz = (bid & 7) * 64 + (bid >> 3);  // bijective XCD swizzle (512%8==0)
    const int b = swz >> 5;
    const int qt = swz & 31;
    const int qbase = qt * 64 + qsub * 16;
    constexpr int NT = NN / 64;  // 32 key-tiles

    const int sl_sub = lane >> 5;
    const int sl_col = (lane & 31) * 16;
    const int vl_row = lane >> 3;
    const size_t vl_off = (size_t)vl_row * (NN * 2) + (size_t)(((lane & 7) ^ vl_row) << 4);

    const short8* qp = (const short8*)(qb + (size_t)(b * NN + qbase + c) * DD + g * 8);
    short8 qf[8];
#pragma unroll
    for (int kc = 0; kc < 8; kc++) qf[kc] = qp[kc * 4];

    const char* kb_bytes = (const char*)(kb + (size_t)(b * NN) * DD);
    const char* vb_bytes = (const char*)(vTb + (size_t)(b * DD) * NN);
    const int kswz = (c & 7) << 4;
    const int pcs = c & 7;

#define STAGE_KV(kt_) do {                                                               \
        const char* gk = kb_bytes + ((size_t)((kt_) * 64 + 8 * w)) * 512;                \
        _Pragma("unroll")                                                                \
        for (int s_ = 0; s_ < 4; s_++) {                                                 \
            int row_lo = 2 * s_ + sl_sub;                                                \
            gload_lds16(gk + (size_t)row_lo * 512 + (sl_col ^ (row_lo << 4)),            \
                        klds + (8 * w + 2 * s_) * 512);                                  \
        }                                                                                \
        const char* gv = vb_bytes + (size_t)(32 * w) * (NN * 2) + (size_t)(kt_) * 128 + vl_off; \
        _Pragma("unroll")                                                                \
        for (int s_ = 0; s_ < 4; s_++) {                                                 \
            gload_lds16(gv + (size_t)(8 * s_) * (NN * 2),                                \
                        vlds + (32 * w + 8 * s_) * 128);                                 \
        }                                                                                \
    } while (0)

    f32x4 oacc[8];
#pragma unroll
    for (int i = 0; i < 8; i++) oacc[i] = (f32x4){0.f, 0.f, 0.f, 0.f};
    float mrun = -INFINITY;
    float lrun = 0.f;
    unsigned int* plw = p_lds + qsub * 512 + c * 32;

    for (int kt = 0; kt < NT; kt++) {
        STAGE_KV(kt);
        asm volatile("s_waitcnt vmcnt(0)" ::: "memory");
        __builtin_amdgcn_s_barrier();  // B1: K+V tile staged
        fence_mem();

        const char* klb = klds + (size_t)(khalf * 32) * 512;
        f32x4 s0 = (f32x4){0.f, 0.f, 0.f, 0.f};
        f32x4 s1 = (f32x4){0.f, 0.f, 0.f, 0.f};
        __builtin_amdgcn_s_setprio(1);
#pragma unroll
        for (int kc = 0; kc < 8; kc++) {
            short8 qv = qf[kc];
            int col = (kc * 64 + g * 16) ^ kswz;
            short8 kf0 = *(const short8*)(klb + (size_t)c * 512 + col);
            short8 kf1 = *(const short8*)(klb + (size_t)(c + 16) * 512 + col);
            s0 = MFMA16(kf0, qv, s0);
            s1 = MFMA16(kf1, qv, s1);
        }
        __builtin_amdgcn_s_setprio(0);

        float t0 = fmaxf(fmaxf(s0[0], s0[1]), fmaxf(s0[2], s0[3]));
        float t1 = fmaxf(fmaxf(s1[0], s1[1]), fmaxf(s1[2], s1[3]));
        float tmo = fmaxf(t0, t1);
        tmo = fmaxf(tmo, __shfl_xor(tmo, 16));
        tmo = fmaxf(tmo, __shfl_xor(tmo, 32));
        if (g == 0) exm[w * 16 + c] = tmo;
        fence_mem();
        __builtin_amdgcn_s_barrier();  // B2: partner max visible
        fence_mem();
        float tmax = fmaxf(tmo, exm[(w ^ 4) * 16 + c]);

        bool need = tmax > mrun + 8.f;
        if (__any(need)) {
            float mn = fmaxf(mrun, tmax);
            float corr = __expf(mrun - mn);
#pragma unroll
            for (int r = 0; r < 4; r++) s0[r] = __expf(s0[r] - mn);
#pragma unroll
            for (int r = 0; r < 4; r++) s1[r] = __expf(s1[r] - mn);
            lrun = lrun * corr + ((s0[0] + s0[1]) + (s0[2] + s0[3])) +
                   ((s1[0] + s1[1]) + (s1[2] + s1[3]));
            mrun = mn;
#pragma unroll
            for (int r = 0; r < 4; r++) {
                float cr = __shfl(corr, 20 * g + r);
#pragma unroll
                for (int nc = 0; nc < 8; nc++) oacc[nc][r] *= cr;
            }
        } else {
#pragma unroll
            for (int r = 0; r < 4; r++) s0[r] = __expf(s0[r] - mrun);
#pragma unroll
            for (int r = 0; r < 4; r++) s1[r] = __expf(s1[r] - mrun);
            lrun += ((s0[0] + s0[1]) + (s0[2] + s0[3])) +
                    ((s1[0] + s1[1]) + (s1[2] + s1[3]));
        }

        {
            int jb0 = khalf * 16 + 2 * g;
            int jb1 = khalf * 16 + 8 + 2 * g;
            unsigned int pw;
#pragma unroll
            for (int h = 0; h < 2; h++) {
                int j = jb0 + h;
                pw = (unsigned int)f2bf(s0[2 * h]) | ((unsigned int)f2bf(s0[2 * h + 1]) << 16);
                plw[(((j >> 2) ^ pcs) << 2) | (j & 3)] = pw;
                j = jb1 + h;
                pw = (unsigned int)f2bf(s1[2 * h]) | ((unsigned int)f2bf(s1[2 * h + 1]) << 16);
                plw[(((j >> 2) ^ pcs) << 2) | (j & 3)] = pw;
            }
        }
        fence_mem();
        __builtin_amdgcn_s_barrier();  // B3: both P halves of every qsub written
        fence_mem();

        short8 pf0 = *(const short8*)(plw + ((g ^ pcs) << 2));
        short8 pf1 = *(const short8*)(plw + (((4 + g) ^ pcs) << 2));
        __builtin_amdgcn_s_setprio(1);
#pragma unroll
        for (int nc = 0; nc < 8; nc++) {
            const char* vr = vlds + (size_t)(dhalf * 128 + nc * 16 + c) * 128;
            short8 vf0 = *(const short8*)(vr + ((g ^ pcs) << 4));
            short8 vf1 = *(const short8*)(vr + (((4 + g) ^ pcs) << 4));
            oacc[nc] = MFMA16(pf0, vf0, oacc[nc]);
            oacc[nc] = MFMA16(pf1, vf1, oacc[nc]);
        }
        __builtin_amdgcn_s_setprio(0);

        fence_mem();
        __builtin_amdgcn_s_barrier();  // B4: tile fully consumed
        fence_mem();
    }
#undef STAGE_KV

    // ---- combine l across pair ----
    float lt = lrun;
    lt += __shfl_xor(lt, 16);
    lt += __shfl_xor(lt, 32);
    if (g == 0) exl[w * 16 + c] = lt;
    fence_mem();
    __builtin_amdgcn_s_barrier();
    fence_mem();
    lt += exl[(w ^ 4) * 16 + c];
    float inv_r[4];
#pragma unroll
    for (int r = 0; r < 4; r++) inv_r[r] = 1.f / __shfl(lt, 20 * g + r);

    // ---- write normalized o-tile into reused LDS ----
    unsigned short* ol = (unsigned short*)smem;
#pragma unroll
    for (int r = 0; r < 4; r++) {
        int row = 4 * g + r;
        int swr = (row & 7) << 3;
#pragma unroll
        for (int nc = 0; nc < 8; nc++) {
            int col = dhalf * 128 + nc * 16 + c;
            ol[qsub * 4096 + row * 256 + (col ^ swr)] = f2bf(oacc[nc][r] * inv_r[r]);
        }
    }
    fence_mem();
    __builtin_amdgcn_s_barrier();  // o-tile complete
    fence_mem();

    // ---- fused FFN2a + gelu + mean: wave w owns output cols [32w, 32w+32) ----
    {
        const int wcol = w * 32;
        float colsum[2] = {0.f, 0.f};
#pragma unroll
        for (int q2 = 0; q2 < 4; q2++) {
            f32x4 acc2[2];
            acc2[0] = (f32x4){0.f, 0.f, 0.f, 0.f};
            acc2[1] = (f32x4){0.f, 0.f, 0.f, 0.f};
            const unsigned short* oq = ol + q2 * 4096;
            const int swc = (c & 7) << 3;
#pragma unroll
            for (int kc = 0; kc < 8; kc++) {
                short8 a = *(const short8*)(oq + c * 256 + ((kc * 32 + g * 8) ^ swc));
#pragma unroll
                for (int nc = 0; nc < 2; nc++) {
                    short8 bfr = *(const short8*)(W2aT + (size_t)(wcol + nc * 16 + c) * 256 + kc * 32 + g * 8);
                    acc2[nc] = MFMA16(a, bfr, acc2[nc]);
                }
            }
#pragma unroll
            for (int nc = 0; nc < 2; nc++) {
                float bv = b2a[wcol + nc * 16 + c];
                float s = 0.f;
#pragma unroll
                for (int r = 0; r < 4; r++) s += gelu_exact(acc2[nc][r] + bv);
                colsum[nc] += s;
            }
        }
#pragma unroll
        for (int nc = 0; nc < 2; nc++) {
            float s = colsum[nc];
            s += __shfl_xor(s, 16);
            s += __shfl_xor(s, 32);
            if (g == 0) atomicAdd(&bar[b * 256 + wcol + nc * 16 + c], s);
        }
    }
}

// ---- final projection ----
__global__ void final_k(const float* __restrict__ bar, const float* __restrict__ W2b,
                        const float* __restrict__ b2b, float* __restrict__ out) {
    int b = blockIdx.x, d = threadIdx.x;
    float s = 0.f;
    for (int h = 0; h < HH; h++) s += bar[b * HH + h] * W2b[h * DD + d];
    out[b * DD + d] = b2b[d] + s * (1.f / (float)NN);
}

extern "C" void kernel_launch(void* const* d_in, const int* in_sizes, int n_in,
                              void* d_out, int out_size, void* d_ws, size_t ws_size,
                              hipStream_t stream) {
    (void)in_sizes; (void)n_in; (void)out_size; (void)ws_size;
    const float* x    = (const float*)d_in[0];
    const float* grd  = (const float*)d_in[1];
    const float* W1a  = (const float*)d_in[2];
    const float* b1a  = (const float*)d_in[3];
    const float* W1b  = (const float*)d_in[4];
    const float* b1b  = (const float*)d_in[5];
    const float* Wqkv = (const float*)d_in[6];
    const float* W2a  = (const float*)d_in[7];
    const float* b2a  = (const float*)d_in[8];
    const float* W2b  = (const float*)d_in[9];
    const float* b2b  = (const float*)d_in[10];
    float* out = (float*)d_out;

    char* ws = (char*)d_ws;
    const size_t MB = 1024 * 1024;
    unsigned short* q_buf  = (unsigned short*)(ws + 0);
    unsigned short* k_buf  = (unsigned short*)(ws + 16 * MB);
    unsigned short* vT_buf = (unsigned short*)(ws + 32 * MB);
    unsigned short* W1bT   = (unsigned short*)(ws + 80 * MB);
    unsigned short* WqkvT  = (unsigned short*)(ws + 80 * MB + 512 * 1024);
    unsigned short* W2aT   = (unsigned short*)(ws + 81 * MB);
    float*          bar    = (float*)(ws + 81 * MB + 256 * 1024);

    transposeT_k<<<dim3(80), 256, 0, stream>>>(W1b, Wqkv, W2a, W1bT, WqkvT, W2aT);
    ffn_qkv_k<<<dim3(512), 512, 0, stream>>>(x, grd, W1a, b1a, W1bT, b1b, WqkvT,
                                             q_buf, k_buf, vT_buf);
    hipMemsetAsync(bar, 0, BB * HH * sizeof(float), stream);
    attn_k<<<dim3(512), 512, 0, stream>>>(q_buf, k_buf, vT_buf, W2aT, b2a, bar);
    final_k<<<dim3(BB), 256, 0, stream>>>(bar, W2b, b2b, out);
}